// Round 1
// baseline (1508.757 us; speedup 1.0000x reference)
//
#include <hip/hip_runtime.h>

#define SS 2048
#define DD 64
#define TQ 64
#define NCHUNK (SS / 64)
#define LSTR 72   // LDS row stride in bf16 elems (64 + 8 pad; keeps 16B alignment)

typedef __attribute__((ext_vector_type(8))) short     short8;
typedef __attribute__((ext_vector_type(8))) __bf16    bf16x8;
typedef __attribute__((ext_vector_type(4))) float     float4v;
typedef __attribute__((ext_vector_type(4))) unsigned short ushort4v;

__device__ __forceinline__ unsigned short f2bf(float x) {
    unsigned u = __float_as_uint(x);
    u += 0x7fffu + ((u >> 16) & 1u);   // round-to-nearest-even
    return (unsigned short)(u >> 16);
}

__device__ __forceinline__ bf16x8 ld_frag(const unsigned short* p) {
    return __builtin_bit_cast(bf16x8, *(const short8*)p);
}

__global__ __launch_bounds__(256, 2) void attn_fused(
    const float* __restrict__ Q, const float* __restrict__ K,
    const float* __restrict__ V, const int* __restrict__ mask,
    float* __restrict__ outp, float* __restrict__ pattn)
{
    __shared__ unsigned short Qs[TQ * LSTR];
    __shared__ unsigned short Ks[64 * LSTR];
    __shared__ unsigned short Vt[64 * LSTR];     // V transposed: [d][key]
    __shared__ unsigned short Pw[4 * 16 * LSTR]; // per-wave p tile [16 q][64 key]
    __shared__ float biasf[64];

    const int tid  = threadIdx.x;
    const int w    = tid >> 6;
    const int lane = tid & 63;
    const int lq   = lane & 15;
    const int quad = lane >> 4;

    const int bh = blockIdx.x;       // bh fastest-varying -> same-bh blocks share XCD
    const int b  = bh >> 4;
    const int q0 = blockIdx.y * TQ;

    const float* Qg = Q + ((size_t)bh * SS + q0) * DD;
    const float* Kg = K + (size_t)bh * SS * DD;
    const float* Vg = V + (size_t)bh * SS * DD;
    const int*   mg = mask + b * SS;

    // ---- stage Q (pre-scaled by 1/sqrt(64)=0.125) as bf16 ----
    #pragma unroll
    for (int it = 0; it < 4; ++it) {
        int e4 = it * 256 + tid;
        int row = e4 >> 4, c4 = e4 & 15;
        float4v v = *(const float4v*)(Qg + e4 * 4);
        ushort4v h;
        h[0] = f2bf(v[0] * 0.125f); h[1] = f2bf(v[1] * 0.125f);
        h[2] = f2bf(v[2] * 0.125f); h[3] = f2bf(v[3] * 0.125f);
        *(ushort4v*)(Qs + row * LSTR + c4 * 4) = h;
    }
    __syncthreads();

    // A-fragments (persist in regs for both passes): row = w*16+lq, k chunks of 8 at quad*8
    bf16x8 a0 = ld_frag(Qs + (w * 16 + lq) * LSTR + quad * 8);
    bf16x8 a1 = ld_frag(Qs + (w * 16 + lq) * LSTR + 32 + quad * 8);

    float m_r[4], l_r[4];
    #pragma unroll
    for (int r = 0; r < 4; ++r) { m_r[r] = -INFINITY; l_r[r] = 0.0f; }

    // =================== PASS 1: row max & sum ===================
    for (int c = 0; c < NCHUNK; ++c) {
        __syncthreads();
        const float* Kc = Kg + (size_t)(c * 64) * DD;
        #pragma unroll
        for (int it = 0; it < 4; ++it) {
            int e4 = it * 256 + tid;
            int row = e4 >> 4, c4 = e4 & 15;
            float4v v = *(const float4v*)(Kc + e4 * 4);
            ushort4v h;
            h[0] = f2bf(v[0]); h[1] = f2bf(v[1]); h[2] = f2bf(v[2]); h[3] = f2bf(v[3]);
            *(ushort4v*)(Ks + row * LSTR + c4 * 4) = h;
        }
        if (tid < 64) biasf[tid] = (mg[c * 64 + tid] == 0) ? -1e9f : 0.0f;
        __syncthreads();

        float4v sc[4];
        #pragma unroll
        for (int t = 0; t < 4; ++t) {
            float bias = biasf[t * 16 + lq];
            float4v acc = {bias, bias, bias, bias};
            bf16x8 b0 = ld_frag(Ks + (t * 16 + lq) * LSTR + quad * 8);
            bf16x8 b1 = ld_frag(Ks + (t * 16 + lq) * LSTR + 32 + quad * 8);
            acc = __builtin_amdgcn_mfma_f32_16x16x32_bf16(a0, b0, acc, 0, 0, 0);
            acc = __builtin_amdgcn_mfma_f32_16x16x32_bf16(a1, b1, acc, 0, 0, 0);
            sc[t] = acc;
        }
        #pragma unroll
        for (int r = 0; r < 4; ++r) {
            float mx = fmaxf(fmaxf(sc[0][r], sc[1][r]), fmaxf(sc[2][r], sc[3][r]));
            float mn = fmaxf(m_r[r], mx);
            float sum = __expf(sc[0][r] - mn) + __expf(sc[1][r] - mn)
                      + __expf(sc[2][r] - mn) + __expf(sc[3][r] - mn);
            l_r[r] = l_r[r] * __expf(m_r[r] - mn) + sum;
            m_r[r] = mn;
        }
    }

    // butterfly reduce (m,l) across the 16 lanes holding one row's columns
    #pragma unroll
    for (int r = 0; r < 4; ++r) {
        float m = m_r[r], l = l_r[r];
        #pragma unroll
        for (int off = 1; off < 16; off <<= 1) {
            float mo = __shfl_xor(m, off, 64);
            float lo = __shfl_xor(l, off, 64);
            float mn = fmaxf(m, mo);
            l = l * __expf(m - mn) + lo * __expf(mo - mn);
            m = mn;
        }
        m_r[r] = m;
        l_r[r] = 1.0f / l;   // keep reciprocal
    }

    // =================== PASS 2: p, p_attn stores, PV ===================
    float4v oacc[4];
    #pragma unroll
    for (int t = 0; t < 4; ++t) oacc[t] = (float4v){0.f, 0.f, 0.f, 0.f};

    unsigned short* pw = Pw + w * 16 * LSTR;

    for (int c = 0; c < NCHUNK; ++c) {
        __syncthreads();
        const float* Kc = Kg + (size_t)(c * 64) * DD;
        const float* Vc = Vg + (size_t)(c * 64) * DD;
        #pragma unroll
        for (int it = 0; it < 4; ++it) {
            int e4 = it * 256 + tid;
            int row = e4 >> 4, c4 = e4 & 15;
            float4v v = *(const float4v*)(Kc + e4 * 4);
            ushort4v h;
            h[0] = f2bf(v[0]); h[1] = f2bf(v[1]); h[2] = f2bf(v[2]); h[3] = f2bf(v[3]);
            *(ushort4v*)(Ks + row * LSTR + c4 * 4) = h;
            float4v vv = *(const float4v*)(Vc + e4 * 4);
            Vt[(c4 * 4 + 0) * LSTR + row] = f2bf(vv[0]);
            Vt[(c4 * 4 + 1) * LSTR + row] = f2bf(vv[1]);
            Vt[(c4 * 4 + 2) * LSTR + row] = f2bf(vv[2]);
            Vt[(c4 * 4 + 3) * LSTR + row] = f2bf(vv[3]);
        }
        if (tid < 64) biasf[tid] = (mg[c * 64 + tid] == 0) ? -1e9f : 0.0f;
        __syncthreads();

        float4v sc[4];
        #pragma unroll
        for (int t = 0; t < 4; ++t) {
            float bias = biasf[t * 16 + lq];
            float4v acc = {bias, bias, bias, bias};
            bf16x8 b0 = ld_frag(Ks + (t * 16 + lq) * LSTR + quad * 8);
            bf16x8 b1 = ld_frag(Ks + (t * 16 + lq) * LSTR + 32 + quad * 8);
            acc = __builtin_amdgcn_mfma_f32_16x16x32_bf16(a0, b0, acc, 0, 0, 0);
            acc = __builtin_amdgcn_mfma_f32_16x16x32_bf16(a1, b1, acc, 0, 0, 0);
            sc[t] = acc;
        }

        // normalize, store p_attn (fp32), stage p (bf16) for PV A-fragments
        float* pg = pattn + ((size_t)bh * SS + (q0 + w * 16 + quad * 4)) * SS + c * 64;
        #pragma unroll
        for (int t = 0; t < 4; ++t) {
            #pragma unroll
            for (int r = 0; r < 4; ++r) {
                float p = __expf(sc[t][r] - m_r[r]) * l_r[r];
                pg[(size_t)r * SS + t * 16 + lq] = p;
                pw[(quad * 4 + r) * LSTR + t * 16 + lq] = f2bf(p);
            }
        }
        __syncthreads();   // p LDS write -> A-frag read (also covers cross-wave none)

        #pragma unroll
        for (int ks = 0; ks < 2; ++ks) {
            bf16x8 pa = ld_frag(pw + lq * LSTR + ks * 32 + quad * 8);
            #pragma unroll
            for (int t = 0; t < 4; ++t) {
                bf16x8 vb = ld_frag(Vt + (t * 16 + lq) * LSTR + ks * 32 + quad * 8);
                oacc[t] = __builtin_amdgcn_mfma_f32_16x16x32_bf16(pa, vb, oacc[t], 0, 0, 0);
            }
        }
    }

    // ---- store out ----
    float* og = outp + ((size_t)bh * SS + (q0 + w * 16 + quad * 4)) * DD;
    #pragma unroll
    for (int t = 0; t < 4; ++t) {
        #pragma unroll
        for (int r = 0; r < 4; ++r) {
            og[(size_t)r * DD + t * 16 + lq] = oacc[t][r];
        }
    }
}

extern "C" void kernel_launch(void* const* d_in, const int* in_sizes, int n_in,
                              void* d_out, int out_size, void* d_ws, size_t ws_size,
                              hipStream_t stream) {
    const float* Q    = (const float*)d_in[0];
    const float* K    = (const float*)d_in[1];
    const float* V    = (const float*)d_in[2];
    const int*   mask = (const int*)d_in[3];
    float* outp  = (float*)d_out;
    float* pattn = outp + (size_t)4 * 16 * 2048 * 64;   // out is first in tuple

    dim3 grid(64, SS / TQ);   // (bh, q-tile)
    attn_fused<<<grid, 256, 0, stream>>>(Q, K, V, mask, outp, pattn);
}